// Round 9
// baseline (199.295 us; speedup 1.0000x reference)
//
#include <hip/hip_runtime.h>
#include <hip/hip_bf16.h>
#include <math.h>

#define Bn 16
#define Tn 512
#define HIDn 1024
#define NHn 8
#define NKVn 4
#define Dn 128

typedef __attribute__((ext_vector_type(8))) short short8;
typedef __attribute__((ext_vector_type(4))) float floatx4;

__device__ __forceinline__ short bf16r(float f) {
  __hip_bfloat16 h = __float2bfloat16(f);
  return *(short*)&h;
}
__device__ __forceinline__ float bf16f(short s) {
  __hip_bfloat16 h = *(__hip_bfloat16*)&s;
  return __bfloat162float(h);
}

// async 16B global->LDS (dest = wave-uniform base + lane*16)
__device__ __forceinline__ void g2l16(const short* g, short* l) {
  __builtin_amdgcn_global_load_lds(
      (const __attribute__((address_space(1))) void*)g,
      (__attribute__((address_space(3))) void*)l, 16, 0, 0);
}

// ---------------- prep: cast X + transpose-cast all 4 weights, one launch ----------------
__global__ __launch_bounds__(256) void prep_kernel(const float* __restrict__ X,
                                                   const float* __restrict__ Wq,
                                                   const float* __restrict__ Wk,
                                                   const float* __restrict__ Wv,
                                                   const float* __restrict__ Wo,
                                                   short* __restrict__ Xb,
                                                   short* __restrict__ BtQKV,
                                                   short* __restrict__ Wot) {
  __shared__ float tile[32][33];
  int bid = blockIdx.x;
  if (bid < 4096) {
    int i = bid * 256 + threadIdx.x;
    const float4* p = reinterpret_cast<const float4*>(X) + (size_t)i * 2;
    float4 a = p[0], b = p[1];
    short8 o;
    o[0] = bf16r(a.x); o[1] = bf16r(a.y); o[2] = bf16r(a.z); o[3] = bf16r(a.w);
    o[4] = bf16r(b.x); o[5] = bf16r(b.y); o[6] = bf16r(b.z); o[7] = bf16r(b.w);
    reinterpret_cast<short8*>(Xb)[i] = o;
    return;
  }
  int t = bid - 4096;
  const float* in;
  short* out;
  int N;
  if (t < 1024)      { in = Wq; out = BtQKV;               N = 1024; }
  else if (t < 1536) { t -= 1024; in = Wk; out = BtQKV + 1024 * 1024; N = 512; }
  else if (t < 2048) { t -= 1536; in = Wv; out = BtQKV + 1536 * 1024; N = 512; }
  else               { t -= 2048; in = Wo; out = Wot;                N = 1024; }
  int ntx = N >> 5;
  int n0 = (t % ntx) * 32, k0 = (t / ntx) * 32;
  int tx = threadIdx.x & 31, ty = threadIdx.x >> 5;
  for (int i = 0; i < 32; i += 8)
    tile[ty + i][tx] = in[(size_t)(k0 + ty + i) * N + n0 + tx];
  __syncthreads();
  for (int i = 0; i < 32; i += 8)
    out[(size_t)(n0 + ty + i) * 1024 + k0 + tx] = bf16r(tile[tx][ty + i]);
}

// ---------------- GEMM1 fused: Cqkv = Xb @ BtQKV^T, epilogue ropes K / transposes V ----
// 128x128 tile, BK=64, XOR-swizzled g2l16 staging (0 conflicts, R4).
// blockIdx.x 0-7: Q tiles -> plain bf16 store to Cqkv
// blockIdx.x 8-11: K head tiles -> LDS roundtrip, RoPE, store to Cqkv
// blockIdx.x 12-15: V head tiles -> LDS roundtrip, transpose, store to Vt
__global__ __launch_bounds__(256) void gemm_qkv(const short* __restrict__ A,
                                                const short* __restrict__ Bt,
                                                short* __restrict__ Cqkv,
                                                short* __restrict__ Vt) {
  __shared__ __align__(16) short SH[128 * 136]; // staging uses [0,16384); epilogue full
  short* As = SH;
  short* Bs = SH + 128 * 64;
  const int K = 1024, N = 2048;
  const int tid = threadIdx.x;
  const int wave = tid >> 6, lane = tid & 63;
  const int quad = lane >> 4, l16 = lane & 15;
  const int wrow = wave >> 1, wcol = wave & 1;
  const int m0 = blockIdx.y * 128, n0 = blockIdx.x * 128;
  floatx4 acc[4][4];
  for (int mi = 0; mi < 4; ++mi)
    for (int ni = 0; ni < 4; ++ni)
      acc[mi][ni] = (floatx4){0.f, 0.f, 0.f, 0.f};

  for (int kt = 0; kt < K; kt += 64) {
#pragma unroll
    for (int v = 0; v < 4; ++v) {
      int s = tid + v * 256;
      int r = s >> 3;
      int c = (s & 7) ^ (r & 7);
      short* dstA = As + (size_t)(v * 256 + wave * 64) * 8;
      g2l16(&A[(size_t)(m0 + r) * K + kt + c * 8], dstA);
      short* dstB = Bs + (size_t)(v * 256 + wave * 64) * 8;
      g2l16(&Bt[(size_t)(n0 + r) * K + kt + c * 8], dstB);
    }
    __syncthreads();
#pragma unroll
    for (int kc = 0; kc < 2; ++kc) {
      short8 af[4], bfr[4];
#pragma unroll
      for (int mi = 0; mi < 4; ++mi) {
        int R = wrow * 64 + mi * 16 + l16;
        int pos = (kc * 4 + quad) ^ (R & 7);
        af[mi] = *(short8*)&As[R * 64 + pos * 8];
      }
#pragma unroll
      for (int ni = 0; ni < 4; ++ni) {
        int R = wcol * 64 + ni * 16 + l16;
        int pos = (kc * 4 + quad) ^ (R & 7);
        bfr[ni] = *(short8*)&Bs[R * 64 + pos * 8];
      }
#pragma unroll
      for (int mi = 0; mi < 4; ++mi)
#pragma unroll
        for (int ni = 0; ni < 4; ++ni)
          acc[mi][ni] = __builtin_amdgcn_mfma_f32_16x16x32_bf16(af[mi], bfr[ni], acc[mi][ni], 0, 0, 0);
    }
    __syncthreads();
  }

  const int bx = blockIdx.x;
  if (bx < 8) {
    // ---- Q tiles: plain store ----
#pragma unroll
    for (int mi = 0; mi < 4; ++mi)
#pragma unroll
      for (int ni = 0; ni < 4; ++ni)
#pragma unroll
        for (int r = 0; r < 4; ++r) {
          int row = m0 + wrow * 64 + mi * 16 + quad * 4 + r;
          int col = n0 + wcol * 64 + ni * 16 + l16;
          Cqkv[(size_t)row * N + col] = bf16r(acc[mi][ni][r]);
        }
  } else if (bx < 12) {
    // ---- K tiles: LDS roundtrip + RoPE (pairs (d,d+64) within this head tile) ----
#pragma unroll
    for (int mi = 0; mi < 4; ++mi)
#pragma unroll
      for (int ni = 0; ni < 4; ++ni)
#pragma unroll
        for (int r = 0; r < 4; ++r) {
          int tl = wrow * 64 + mi * 16 + quad * 4 + r;   // local row (t)
          int cl = wcol * 64 + ni * 16 + l16;            // local col (d)
          SH[tl * 136 + cl] = bf16r(acc[mi][ni][r]);
        }
    __syncthreads();
    // 1024 chunks: row=c>>3 in [0,128), d0=(c&7)*8 in [0,64); each writes d0 AND d0+64
#pragma unroll
    for (int k2 = 0; k2 < 4; ++k2) {
      int c = k2 * 256 + tid;
      int row = c >> 3, d0 = (c & 7) << 3;
      float tf = (float)((m0 + row) & (Tn - 1));
      short8 x1 = *(short8*)&SH[row * 136 + d0];
      short8 x2 = *(short8*)&SH[row * 136 + d0 + 64];
      short8 o1, o2;
#pragma unroll
      for (int j = 0; j < 8; ++j) {
        float a = tf * exp2f(-0.2076205059f * (float)(d0 + j)); // log2(10000)/64
        float s, cc;
        sincosf(a, &s, &cc);
        float v1 = bf16f(x1[j]), v2 = bf16f(x2[j]);
        o1[j] = bf16r(v1 * cc - v2 * s);
        o2[j] = bf16r(v2 * cc + v1 * s);
      }
      size_t base = (size_t)(m0 + row) * N + n0 + d0;
      *(short8*)&Cqkv[base] = o1;
      *(short8*)&Cqkv[base + 64] = o2;
    }
  } else {
    // ---- V tiles: LDS transpose -> Vt (B,NKV,D,T) ----
#pragma unroll
    for (int mi = 0; mi < 4; ++mi)
#pragma unroll
      for (int ni = 0; ni < 4; ++ni)
#pragma unroll
        for (int r = 0; r < 4; ++r) {
          int tl = wrow * 64 + mi * 16 + quad * 4 + r;
          int dl = wcol * 64 + ni * 16 + l16;
          SH[dl * 136 + tl] = bf16r(acc[mi][ni][r]);   // [d][t]
        }
    __syncthreads();
    int kv = bx - 12, b = m0 >> 9, t0 = m0 & (Tn - 1);
    // FULL tile: 2048 chunks: d=c>>4 in [0,128), toff=(c&15)*8 in [0,128)
    // (R8 bug: k2<4 with toff=(c&7)*8 covered only t<64 -> half of Vt stayed poisoned)
#pragma unroll
    for (int k2 = 0; k2 < 8; ++k2) {
      int c = k2 * 256 + tid;
      int d = c >> 4, toff = (c & 15) << 3;
      short8 v = *(short8*)&SH[d * 136 + toff];
      *(short8*)&Vt[((size_t)(b * NKVn + kv) * 128 + d) * Tn + t0 + toff] = v;
    }
  }
}

// ---------------- GEMM 128x128 (gemm2): C = A(MxK) * Bt(NxK)^T, f32 out ----------------
// NOTE (R6): do NOT narrow the tile; drain-bound, narrower tile = fewer MFMA per drain.
template <bool OUTF32>
__global__ __launch_bounds__(256) void gemm_bt(const short* __restrict__ A,
                                               const short* __restrict__ Bt,
                                               void* __restrict__ Cout,
                                               int M, int N, int K) {
  __shared__ __align__(16) short As[128 * 64];
  __shared__ __align__(16) short Bs[128 * 64];
  const int tid = threadIdx.x;
  const int wave = tid >> 6, lane = tid & 63;
  const int quad = lane >> 4, l16 = lane & 15;
  const int wrow = wave >> 1, wcol = wave & 1;
  const int m0 = blockIdx.y * 128, n0 = blockIdx.x * 128;
  floatx4 acc[4][4];
  for (int mi = 0; mi < 4; ++mi)
    for (int ni = 0; ni < 4; ++ni)
      acc[mi][ni] = (floatx4){0.f, 0.f, 0.f, 0.f};

  for (int kt = 0; kt < K; kt += 64) {
#pragma unroll
    for (int v = 0; v < 4; ++v) {
      int s = tid + v * 256;
      int r = s >> 3;
      int c = (s & 7) ^ (r & 7);
      short* dstA = (short*)As + (size_t)(v * 256 + wave * 64) * 8;
      g2l16(&A[(size_t)(m0 + r) * K + kt + c * 8], dstA);
      short* dstB = (short*)Bs + (size_t)(v * 256 + wave * 64) * 8;
      g2l16(&Bt[(size_t)(n0 + r) * K + kt + c * 8], dstB);
    }
    __syncthreads();
#pragma unroll
    for (int kc = 0; kc < 2; ++kc) {
      short8 af[4], bfr[4];
#pragma unroll
      for (int mi = 0; mi < 4; ++mi) {
        int R = wrow * 64 + mi * 16 + l16;
        int pos = (kc * 4 + quad) ^ (R & 7);
        af[mi] = *(short8*)&As[R * 64 + pos * 8];
      }
#pragma unroll
      for (int ni = 0; ni < 4; ++ni) {
        int R = wcol * 64 + ni * 16 + l16;
        int pos = (kc * 4 + quad) ^ (R & 7);
        bfr[ni] = *(short8*)&Bs[R * 64 + pos * 8];
      }
#pragma unroll
      for (int mi = 0; mi < 4; ++mi)
#pragma unroll
        for (int ni = 0; ni < 4; ++ni)
          acc[mi][ni] = __builtin_amdgcn_mfma_f32_16x16x32_bf16(af[mi], bfr[ni], acc[mi][ni], 0, 0, 0);
    }
    __syncthreads();
  }
#pragma unroll
  for (int mi = 0; mi < 4; ++mi)
#pragma unroll
    for (int ni = 0; ni < 4; ++ni)
#pragma unroll
      for (int r = 0; r < 4; ++r) {
        int row = m0 + wrow * 64 + mi * 16 + quad * 4 + r;
        int col = n0 + wcol * 64 + ni * 16 + l16;
        if (OUTF32)
          ((float*)Cout)[(size_t)row * N + col] = acc[mi][ni][r];
        else
          ((short*)Cout)[(size_t)row * N + col] = bf16r(acc[mi][ni][r]);
      }
}

// ---------------- Flash attention ----------------
// 1024 blocks, qt-major reversed (LPT). 64 q rows/block, 4 waves x 16 rows.
// Fixed-max softmax, scale folded into q-frag, Q-RoPE in-register,
// g2l16 + XOR-swizzled staging (0 conflicts).
__global__ __launch_bounds__(256) void attn_kernel(const short* __restrict__ Cqkv,
                                                   const short* __restrict__ Vt,
                                                   short* __restrict__ Aout) {
  __shared__ __align__(16) short Ks[64 * 128];  // keys x d, chunk pos = c ^ (r&15)
  __shared__ __align__(16) short Vs[128 * 64];  // d x keys, chunk pos = c ^ (r&7)
  __shared__ short Ps[4][16][72];               // per-wave P (C->A layout round trip)
  const int tid = threadIdx.x;
  const int wave = tid >> 6, lane = tid & 63;
  const int quad = lane >> 4, l16 = lane & 15;
  const int blk = blockIdx.x;
  const int qt = 7 - (blk >> 7);    // heavy q-tiles dispatch first
  const int h = blk & 7, b = (blk >> 3) & 15;
  const int kvh = h >> 1;
  const short* Qp = Cqkv + (size_t)b * Tn * 2048 + h * 128;
  const short* Kp = Cqkv + (size_t)b * Tn * 2048 + 1024 + kvh * 128;
  const short* Vtp = Vt + (size_t)(b * NKVn + kvh) * 128 * Tn;

  const int qrow0 = qt * 64 + wave * 16;
  const float scale = 0.08838834764831845f; // 1/sqrt(128)

  short8 qf[4];
#pragma unroll
  for (int kc = 0; kc < 4; ++kc)
    qf[kc] = *(const short8*)&Qp[(size_t)(qrow0 + l16) * 2048 + kc * 32 + quad * 8];
  {
    float tf = (float)(qrow0 + l16);
#pragma unroll
    for (int kc = 0; kc < 2; ++kc)
#pragma unroll
      for (int j = 0; j < 8; ++j) {
        int d = kc * 32 + quad * 8 + j;
        float a = tf * exp2f(-0.2076205059f * (float)d);
        float s, c;
        sincosf(a, &s, &c);
        float x1 = bf16f(qf[kc][j]), x2 = bf16f(qf[kc + 2][j]);
        qf[kc][j] = bf16r((x1 * c - x2 * s) * scale);
        qf[kc + 2][j] = bf16r((x2 * c + x1 * s) * scale);
      }
  }

  floatx4 o[8];
  float l_part[4];
#pragma unroll
  for (int ni = 0; ni < 8; ++ni) o[ni] = (floatx4){0.f, 0.f, 0.f, 0.f};
#pragma unroll
  for (int r = 0; r < 4; ++r) l_part[r] = 0.f;

  const int nk = qt * 64 + 64;

  for (int k0 = 0; k0 < nk; k0 += 64) {
#pragma unroll
    for (int v = 0; v < 4; ++v) {
      int s = tid + v * 256;
      int r = s >> 4, c = (s & 15) ^ (r & 15);
      short* dstK = (short*)Ks + (size_t)(v * 256 + wave * 64) * 8;
      g2l16(&Kp[(size_t)(k0 + r) * 2048 + c * 8], dstK);
    }
#pragma unroll
    for (int v = 0; v < 4; ++v) {
      int s = tid + v * 256;
      int r = s >> 3, c = (s & 7) ^ (r & 7);
      short* dstV = (short*)Vs + (size_t)(v * 256 + wave * 64) * 8;
      g2l16(&Vtp[(size_t)r * Tn + k0 + c * 8], dstV);
    }
    __syncthreads();

    floatx4 s[4];
#pragma unroll
    for (int ni = 0; ni < 4; ++ni) {
      s[ni] = (floatx4){0.f, 0.f, 0.f, 0.f};
      short8 kf[4];
#pragma unroll
      for (int kc = 0; kc < 4; ++kc) {
        int R = ni * 16 + l16;
        int pos = (kc * 4 + quad) ^ (R & 15);
        kf[kc] = *(short8*)&Ks[R * 128 + pos * 8];
      }
#pragma unroll
      for (int kc = 0; kc < 4; ++kc)
        s[ni] = __builtin_amdgcn_mfma_f32_16x16x32_bf16(qf[kc], kf[kc], s[ni], 0, 0, 0);
    }

    const bool diag = (k0 + 63 > qrow0);
#pragma unroll
    for (int ni = 0; ni < 4; ++ni)
#pragma unroll
      for (int r = 0; r < 4; ++r) {
        float p = __expf(s[ni][r]);
        if (diag) {
          int key = k0 + ni * 16 + l16;
          int qr = qrow0 + quad * 4 + r;
          if (key > qr) p = 0.f;
        }
        s[ni][r] = p;
        l_part[r] += p;
      }

#pragma unroll
    for (int ni = 0; ni < 4; ++ni)
#pragma unroll
      for (int r = 0; r < 4; ++r)
        Ps[wave][quad * 4 + r][ni * 16 + l16] = bf16r(s[ni][r]);

    short8 pf[2];
#pragma unroll
    for (int kc = 0; kc < 2; ++kc)
      pf[kc] = *(short8*)&Ps[wave][l16][kc * 32 + quad * 8];
#pragma unroll
    for (int ni = 0; ni < 8; ++ni) {
      int R = ni * 16 + l16;
      int pos0 = quad ^ (R & 7);
      int pos1 = (4 + quad) ^ (R & 7);
      short8 vf0 = *(short8*)&Vs[R * 64 + pos0 * 8];
      short8 vf1 = *(short8*)&Vs[R * 64 + pos1 * 8];
      o[ni] = __builtin_amdgcn_mfma_f32_16x16x32_bf16(pf[0], vf0, o[ni], 0, 0, 0);
      o[ni] = __builtin_amdgcn_mfma_f32_16x16x32_bf16(pf[1], vf1, o[ni], 0, 0, 0);
    }
    __syncthreads();
  }

  float inv[4];
#pragma unroll
  for (int r = 0; r < 4; ++r) {
    float rs = l_part[r];
#pragma unroll
    for (int off = 8; off >= 1; off >>= 1) rs += __shfl_xor(rs, off, 16);
    inv[r] = 1.0f / rs;
  }
#pragma unroll
  for (int ni = 0; ni < 8; ++ni)
#pragma unroll
    for (int r = 0; r < 4; ++r) {
      int t = qrow0 + quad * 4 + r;
      int d = ni * 16 + l16;
      Aout[((size_t)b * Tn + t) * 1024 + h * 128 + d] = bf16r(o[ni][r] * inv[r]);
    }
}

extern "C" void kernel_launch(void* const* d_in, const int* in_sizes, int n_in,
                              void* d_out, int out_size, void* d_ws, size_t ws_size,
                              hipStream_t stream) {
  const float* X  = (const float*)d_in[0];
  const float* Wq = (const float*)d_in[1];
  const float* Wk = (const float*)d_in[2];
  const float* Wv = (const float*)d_in[3];
  const float* Wo = (const float*)d_in[4];

  char* ws = (char*)d_ws;
  short* Xb    = (short*)(ws);                 // 8192x1024 bf16 = 16 MB
  short* BtQKV = (short*)(ws + (16ull << 20)); // 2048x1024 bf16 = 4 MB
  short* Wot   = (short*)(ws + (20ull << 20)); // 1024x1024 bf16 = 2 MB
  short* Cqkv  = (short*)(ws + (22ull << 20)); // 8192x2048 bf16 = 32 MB (V region dead)
  short* Vt    = (short*)(ws + (54ull << 20)); // 16x4x128x512 bf16 = 8 MB
  short* Aout  = (short*)(ws + (62ull << 20)); // 8192x1024 bf16 = 16 MB (end 78 MB)

  prep_kernel<<<7168, 256, 0, stream>>>(X, Wq, Wk, Wv, Wo, Xb, BtQKV, Wot);
  gemm_qkv<<<dim3(16, 64), 256, 0, stream>>>(Xb, BtQKV, Cqkv, Vt);
  attn_kernel<<<1024, 256, 0, stream>>>(Cqkv, Vt, Aout);
  gemm_bt<true><<<dim3(8, 64), 256, 0, stream>>>(Aout, Wot, d_out, 8192, 1024, 1024);
}

// Round 10
// 193.241 us; speedup vs baseline: 1.0313x; 1.0313x over previous
//
#include <hip/hip_runtime.h>
#include <hip/hip_bf16.h>
#include <math.h>

#define Bn 16
#define Tn 512
#define HIDn 1024
#define NHn 8
#define NKVn 4
#define Dn 128

typedef __attribute__((ext_vector_type(8))) short short8;
typedef __attribute__((ext_vector_type(4))) float floatx4;

__device__ __forceinline__ short bf16r(float f) {
  __hip_bfloat16 h = __float2bfloat16(f);
  return *(short*)&h;
}
__device__ __forceinline__ float bf16f(short s) {
  __hip_bfloat16 h = *(__hip_bfloat16*)&s;
  return __bfloat162float(h);
}

// async 16B global->LDS (dest = wave-uniform base + lane*16)
__device__ __forceinline__ void g2l16(const short* g, short* l) {
  __builtin_amdgcn_global_load_lds(
      (const __attribute__((address_space(1))) void*)g,
      (__attribute__((address_space(3))) void*)l, 16, 0, 0);
}

// ---------------- prep: cast X + transpose-cast all 4 weights, one launch ----------------
__global__ __launch_bounds__(256) void prep_kernel(const float* __restrict__ X,
                                                   const float* __restrict__ Wq,
                                                   const float* __restrict__ Wk,
                                                   const float* __restrict__ Wv,
                                                   const float* __restrict__ Wo,
                                                   short* __restrict__ Xb,
                                                   short* __restrict__ BtQKV,
                                                   short* __restrict__ Wot) {
  __shared__ float tile[32][33];
  int bid = blockIdx.x;
  if (bid < 4096) {
    int i = bid * 256 + threadIdx.x;
    const float4* p = reinterpret_cast<const float4*>(X) + (size_t)i * 2;
    float4 a = p[0], b = p[1];
    short8 o;
    o[0] = bf16r(a.x); o[1] = bf16r(a.y); o[2] = bf16r(a.z); o[3] = bf16r(a.w);
    o[4] = bf16r(b.x); o[5] = bf16r(b.y); o[6] = bf16r(b.z); o[7] = bf16r(b.w);
    reinterpret_cast<short8*>(Xb)[i] = o;
    return;
  }
  int t = bid - 4096;
  const float* in;
  short* out;
  int N;
  if (t < 1024)      { in = Wq; out = BtQKV;               N = 1024; }
  else if (t < 1536) { t -= 1024; in = Wk; out = BtQKV + 1024 * 1024; N = 512; }
  else if (t < 2048) { t -= 1536; in = Wv; out = BtQKV + 1536 * 1024; N = 512; }
  else               { t -= 2048; in = Wo; out = Wot;                N = 1024; }
  int ntx = N >> 5;
  int n0 = (t % ntx) * 32, k0 = (t / ntx) * 32;
  int tx = threadIdx.x & 31, ty = threadIdx.x >> 5;
  for (int i = 0; i < 32; i += 8)
    tile[ty + i][tx] = in[(size_t)(k0 + ty + i) * N + n0 + tx];
  __syncthreads();
  for (int i = 0; i < 32; i += 8)
    out[(size_t)(n0 + ty + i) * 1024 + k0 + tx] = bf16r(tile[tx][ty + i]);
}

// ---------------- GEMM1 fused: Cqkv = Xb @ BtQKV^T, epilogue transposes V ----
// 128x128 tile, BK=64, XOR-swizzled g2l16 staging (0 conflicts, R4).
// blockIdx.x 0-11: Q/K tiles -> plain bf16 store to Cqkv (K roped by rope_k after)
// blockIdx.x 12-15: V head tiles -> LDS roundtrip transpose -> Vt
// NOTE (R9): K-RoPE fused here cost VGPR 76->108 (occupancy 21->15%, +13.5 us) --
// transcendentals must stay OUT of this kernel (G6). V copy epilogue is register-cheap.
__global__ __launch_bounds__(256) void gemm_qkv(const short* __restrict__ A,
                                                const short* __restrict__ Bt,
                                                short* __restrict__ Cqkv,
                                                short* __restrict__ Vt) {
  __shared__ __align__(16) short SH[128 * 136]; // staging uses [0,16384); V epilogue full
  short* As = SH;
  short* Bs = SH + 128 * 64;
  const int K = 1024, N = 2048;
  const int tid = threadIdx.x;
  const int wave = tid >> 6, lane = tid & 63;
  const int quad = lane >> 4, l16 = lane & 15;
  const int wrow = wave >> 1, wcol = wave & 1;
  const int m0 = blockIdx.y * 128, n0 = blockIdx.x * 128;
  floatx4 acc[4][4];
  for (int mi = 0; mi < 4; ++mi)
    for (int ni = 0; ni < 4; ++ni)
      acc[mi][ni] = (floatx4){0.f, 0.f, 0.f, 0.f};

  for (int kt = 0; kt < K; kt += 64) {
#pragma unroll
    for (int v = 0; v < 4; ++v) {
      int s = tid + v * 256;
      int r = s >> 3;
      int c = (s & 7) ^ (r & 7);
      short* dstA = As + (size_t)(v * 256 + wave * 64) * 8;
      g2l16(&A[(size_t)(m0 + r) * K + kt + c * 8], dstA);
      short* dstB = Bs + (size_t)(v * 256 + wave * 64) * 8;
      g2l16(&Bt[(size_t)(n0 + r) * K + kt + c * 8], dstB);
    }
    __syncthreads();
#pragma unroll
    for (int kc = 0; kc < 2; ++kc) {
      short8 af[4], bfr[4];
#pragma unroll
      for (int mi = 0; mi < 4; ++mi) {
        int R = wrow * 64 + mi * 16 + l16;
        int pos = (kc * 4 + quad) ^ (R & 7);
        af[mi] = *(short8*)&As[R * 64 + pos * 8];
      }
#pragma unroll
      for (int ni = 0; ni < 4; ++ni) {
        int R = wcol * 64 + ni * 16 + l16;
        int pos = (kc * 4 + quad) ^ (R & 7);
        bfr[ni] = *(short8*)&Bs[R * 64 + pos * 8];
      }
#pragma unroll
      for (int mi = 0; mi < 4; ++mi)
#pragma unroll
        for (int ni = 0; ni < 4; ++ni)
          acc[mi][ni] = __builtin_amdgcn_mfma_f32_16x16x32_bf16(af[mi], bfr[ni], acc[mi][ni], 0, 0, 0);
    }
    __syncthreads();
  }

  const int bx = blockIdx.x;
  if (bx < 12) {
    // ---- Q and K tiles: plain store (RoPE on K applied by rope_k kernel) ----
#pragma unroll
    for (int mi = 0; mi < 4; ++mi)
#pragma unroll
      for (int ni = 0; ni < 4; ++ni)
#pragma unroll
        for (int r = 0; r < 4; ++r) {
          int row = m0 + wrow * 64 + mi * 16 + quad * 4 + r;
          int col = n0 + wcol * 64 + ni * 16 + l16;
          Cqkv[(size_t)row * N + col] = bf16r(acc[mi][ni][r]);
        }
  } else {
    // ---- V tiles: LDS transpose -> Vt (B,NKV,D,T); full 128x128 tile ----
#pragma unroll
    for (int mi = 0; mi < 4; ++mi)
#pragma unroll
      for (int ni = 0; ni < 4; ++ni)
#pragma unroll
        for (int r = 0; r < 4; ++r) {
          int tl = wrow * 64 + mi * 16 + quad * 4 + r;
          int dl = wcol * 64 + ni * 16 + l16;
          SH[dl * 136 + tl] = bf16r(acc[mi][ni][r]);   // [d][t]
        }
    __syncthreads();
    int kv = bx - 12, b = m0 >> 9, t0 = m0 & (Tn - 1);
#pragma unroll
    for (int k2 = 0; k2 < 8; ++k2) {
      int c = k2 * 256 + tid;
      int d = c >> 4, toff = (c & 15) << 3;
      short8 v = *(short8*)&SH[d * 136 + toff];
      *(short8*)&Vt[((size_t)(b * NKVn + kv) * 128 + d) * Tn + t0 + toff] = v;
    }
  }
}

// ---------------- RoPE on K only (cols [1024,1536)), vectorized short8 ----------------
__global__ void rope_k_kernel(short* __restrict__ C) {
  int idx = blockIdx.x * blockDim.x + threadIdx.x; // 262144
  int vec = idx & 7;
  int head = (idx >> 3) & 3;
  int bt = idx >> 5;
  int t = bt & (Tn - 1);
  int i0 = vec * 8;
  size_t base = (size_t)bt * 2048 + 1024 + head * 128 + i0;
  short8 x1 = *(short8*)&C[base];
  short8 x2 = *(short8*)&C[base + 64];
  short8 o1, o2;
  float tf = (float)t;
#pragma unroll
  for (int j = 0; j < 8; ++j) {
    float a = tf * exp2f(-0.2076205059f * (float)(i0 + j)); // log2(10000)/64
    float s, c;
    sincosf(a, &s, &c);
    float v1 = bf16f(x1[j]), v2 = bf16f(x2[j]);
    o1[j] = bf16r(v1 * c - v2 * s);
    o2[j] = bf16r(v2 * c + v1 * s);
  }
  *(short8*)&C[base] = o1;
  *(short8*)&C[base + 64] = o2;
}

// ---------------- GEMM 128x128 (gemm2): C = A(MxK) * Bt(NxK)^T, f32 out ----------------
// NOTE (R6): do NOT narrow the tile; drain-bound, narrower tile = fewer MFMA per drain.
template <bool OUTF32>
__global__ __launch_bounds__(256) void gemm_bt(const short* __restrict__ A,
                                               const short* __restrict__ Bt,
                                               void* __restrict__ Cout,
                                               int M, int N, int K) {
  __shared__ __align__(16) short As[128 * 64];
  __shared__ __align__(16) short Bs[128 * 64];
  const int tid = threadIdx.x;
  const int wave = tid >> 6, lane = tid & 63;
  const int quad = lane >> 4, l16 = lane & 15;
  const int wrow = wave >> 1, wcol = wave & 1;
  const int m0 = blockIdx.y * 128, n0 = blockIdx.x * 128;
  floatx4 acc[4][4];
  for (int mi = 0; mi < 4; ++mi)
    for (int ni = 0; ni < 4; ++ni)
      acc[mi][ni] = (floatx4){0.f, 0.f, 0.f, 0.f};

  for (int kt = 0; kt < K; kt += 64) {
#pragma unroll
    for (int v = 0; v < 4; ++v) {
      int s = tid + v * 256;
      int r = s >> 3;
      int c = (s & 7) ^ (r & 7);
      short* dstA = (short*)As + (size_t)(v * 256 + wave * 64) * 8;
      g2l16(&A[(size_t)(m0 + r) * K + kt + c * 8], dstA);
      short* dstB = (short*)Bs + (size_t)(v * 256 + wave * 64) * 8;
      g2l16(&Bt[(size_t)(n0 + r) * K + kt + c * 8], dstB);
    }
    __syncthreads();
#pragma unroll
    for (int kc = 0; kc < 2; ++kc) {
      short8 af[4], bfr[4];
#pragma unroll
      for (int mi = 0; mi < 4; ++mi) {
        int R = wrow * 64 + mi * 16 + l16;
        int pos = (kc * 4 + quad) ^ (R & 7);
        af[mi] = *(short8*)&As[R * 64 + pos * 8];
      }
#pragma unroll
      for (int ni = 0; ni < 4; ++ni) {
        int R = wcol * 64 + ni * 16 + l16;
        int pos = (kc * 4 + quad) ^ (R & 7);
        bfr[ni] = *(short8*)&Bs[R * 64 + pos * 8];
      }
#pragma unroll
      for (int mi = 0; mi < 4; ++mi)
#pragma unroll
        for (int ni = 0; ni < 4; ++ni)
          acc[mi][ni] = __builtin_amdgcn_mfma_f32_16x16x32_bf16(af[mi], bfr[ni], acc[mi][ni], 0, 0, 0);
    }
    __syncthreads();
  }
#pragma unroll
  for (int mi = 0; mi < 4; ++mi)
#pragma unroll
    for (int ni = 0; ni < 4; ++ni)
#pragma unroll
      for (int r = 0; r < 4; ++r) {
        int row = m0 + wrow * 64 + mi * 16 + quad * 4 + r;
        int col = n0 + wcol * 64 + ni * 16 + l16;
        if (OUTF32)
          ((float*)Cout)[(size_t)row * N + col] = acc[mi][ni][r];
        else
          ((short*)Cout)[(size_t)row * N + col] = bf16r(acc[mi][ni][r]);
      }
}

// ---------------- Flash attention ----------------
// 1024 blocks, qt-major reversed (LPT). 64 q rows/block, 4 waves x 16 rows.
// Fixed-max softmax, scale folded into q-frag, Q-RoPE in-register,
// g2l16 + XOR-swizzled staging (0 conflicts).
__global__ __launch_bounds__(256) void attn_kernel(const short* __restrict__ Cqkv,
                                                   const short* __restrict__ Vt,
                                                   short* __restrict__ Aout) {
  __shared__ __align__(16) short Ks[64 * 128];  // keys x d, chunk pos = c ^ (r&15)
  __shared__ __align__(16) short Vs[128 * 64];  // d x keys, chunk pos = c ^ (r&7)
  __shared__ short Ps[4][16][72];               // per-wave P (C->A layout round trip)
  const int tid = threadIdx.x;
  const int wave = tid >> 6, lane = tid & 63;
  const int quad = lane >> 4, l16 = lane & 15;
  const int blk = blockIdx.x;
  const int qt = 7 - (blk >> 7);    // heavy q-tiles dispatch first
  const int h = blk & 7, b = (blk >> 3) & 15;
  const int kvh = h >> 1;
  const short* Qp = Cqkv + (size_t)b * Tn * 2048 + h * 128;
  const short* Kp = Cqkv + (size_t)b * Tn * 2048 + 1024 + kvh * 128;
  const short* Vtp = Vt + (size_t)(b * NKVn + kvh) * 128 * Tn;

  const int qrow0 = qt * 64 + wave * 16;
  const float scale = 0.08838834764831845f; // 1/sqrt(128)

  short8 qf[4];
#pragma unroll
  for (int kc = 0; kc < 4; ++kc)
    qf[kc] = *(const short8*)&Qp[(size_t)(qrow0 + l16) * 2048 + kc * 32 + quad * 8];
  {
    float tf = (float)(qrow0 + l16);
#pragma unroll
    for (int kc = 0; kc < 2; ++kc)
#pragma unroll
      for (int j = 0; j < 8; ++j) {
        int d = kc * 32 + quad * 8 + j;
        float a = tf * exp2f(-0.2076205059f * (float)d);
        float s, c;
        sincosf(a, &s, &c);
        float x1 = bf16f(qf[kc][j]), x2 = bf16f(qf[kc + 2][j]);
        qf[kc][j] = bf16r((x1 * c - x2 * s) * scale);
        qf[kc + 2][j] = bf16r((x2 * c + x1 * s) * scale);
      }
  }

  floatx4 o[8];
  float l_part[4];
#pragma unroll
  for (int ni = 0; ni < 8; ++ni) o[ni] = (floatx4){0.f, 0.f, 0.f, 0.f};
#pragma unroll
  for (int r = 0; r < 4; ++r) l_part[r] = 0.f;

  const int nk = qt * 64 + 64;

  for (int k0 = 0; k0 < nk; k0 += 64) {
#pragma unroll
    for (int v = 0; v < 4; ++v) {
      int s = tid + v * 256;
      int r = s >> 4, c = (s & 15) ^ (r & 15);
      short* dstK = (short*)Ks + (size_t)(v * 256 + wave * 64) * 8;
      g2l16(&Kp[(size_t)(k0 + r) * 2048 + c * 8], dstK);
    }
#pragma unroll
    for (int v = 0; v < 4; ++v) {
      int s = tid + v * 256;
      int r = s >> 3, c = (s & 7) ^ (r & 7);
      short* dstV = (short*)Vs + (size_t)(v * 256 + wave * 64) * 8;
      g2l16(&Vtp[(size_t)r * Tn + k0 + c * 8], dstV);
    }
    __syncthreads();

    floatx4 s[4];
#pragma unroll
    for (int ni = 0; ni < 4; ++ni) {
      s[ni] = (floatx4){0.f, 0.f, 0.f, 0.f};
      short8 kf[4];
#pragma unroll
      for (int kc = 0; kc < 4; ++kc) {
        int R = ni * 16 + l16;
        int pos = (kc * 4 + quad) ^ (R & 15);
        kf[kc] = *(short8*)&Ks[R * 128 + pos * 8];
      }
#pragma unroll
      for (int kc = 0; kc < 4; ++kc)
        s[ni] = __builtin_amdgcn_mfma_f32_16x16x32_bf16(qf[kc], kf[kc], s[ni], 0, 0, 0);
    }

    const bool diag = (k0 + 63 > qrow0);
#pragma unroll
    for (int ni = 0; ni < 4; ++ni)
#pragma unroll
      for (int r = 0; r < 4; ++r) {
        float p = __expf(s[ni][r]);
        if (diag) {
          int key = k0 + ni * 16 + l16;
          int qr = qrow0 + quad * 4 + r;
          if (key > qr) p = 0.f;
        }
        s[ni][r] = p;
        l_part[r] += p;
      }

#pragma unroll
    for (int ni = 0; ni < 4; ++ni)
#pragma unroll
      for (int r = 0; r < 4; ++r)
        Ps[wave][quad * 4 + r][ni * 16 + l16] = bf16r(s[ni][r]);

    short8 pf[2];
#pragma unroll
    for (int kc = 0; kc < 2; ++kc)
      pf[kc] = *(short8*)&Ps[wave][l16][kc * 32 + quad * 8];
#pragma unroll
    for (int ni = 0; ni < 8; ++ni) {
      int R = ni * 16 + l16;
      int pos0 = quad ^ (R & 7);
      int pos1 = (4 + quad) ^ (R & 7);
      short8 vf0 = *(short8*)&Vs[R * 64 + pos0 * 8];
      short8 vf1 = *(short8*)&Vs[R * 64 + pos1 * 8];
      o[ni] = __builtin_amdgcn_mfma_f32_16x16x32_bf16(pf[0], vf0, o[ni], 0, 0, 0);
      o[ni] = __builtin_amdgcn_mfma_f32_16x16x32_bf16(pf[1], vf1, o[ni], 0, 0, 0);
    }
    __syncthreads();
  }

  float inv[4];
#pragma unroll
  for (int r = 0; r < 4; ++r) {
    float rs = l_part[r];
#pragma unroll
    for (int off = 8; off >= 1; off >>= 1) rs += __shfl_xor(rs, off, 16);
    inv[r] = 1.0f / rs;
  }
#pragma unroll
  for (int ni = 0; ni < 8; ++ni)
#pragma unroll
    for (int r = 0; r < 4; ++r) {
      int t = qrow0 + quad * 4 + r;
      int d = ni * 16 + l16;
      Aout[((size_t)b * Tn + t) * 1024 + h * 128 + d] = bf16r(o[ni][r] * inv[r]);
    }
}

extern "C" void kernel_launch(void* const* d_in, const int* in_sizes, int n_in,
                              void* d_out, int out_size, void* d_ws, size_t ws_size,
                              hipStream_t stream) {
  const float* X  = (const float*)d_in[0];
  const float* Wq = (const float*)d_in[1];
  const float* Wk = (const float*)d_in[2];
  const float* Wv = (const float*)d_in[3];
  const float* Wo = (const float*)d_in[4];

  char* ws = (char*)d_ws;
  short* Xb    = (short*)(ws);                 // 8192x1024 bf16 = 16 MB
  short* BtQKV = (short*)(ws + (16ull << 20)); // 2048x1024 bf16 = 4 MB
  short* Wot   = (short*)(ws + (20ull << 20)); // 1024x1024 bf16 = 2 MB
  short* Cqkv  = (short*)(ws + (22ull << 20)); // 8192x2048 bf16 = 32 MB (V region dead)
  short* Vt    = (short*)(ws + (54ull << 20)); // 16x4x128x512 bf16 = 8 MB
  short* Aout  = (short*)(ws + (62ull << 20)); // 8192x1024 bf16 = 16 MB (end 78 MB)

  prep_kernel<<<7168, 256, 0, stream>>>(X, Wq, Wk, Wv, Wo, Xb, BtQKV, Wot);
  gemm_qkv<<<dim3(16, 64), 256, 0, stream>>>(Xb, BtQKV, Cqkv, Vt);
  rope_k_kernel<<<1024, 256, 0, stream>>>(Cqkv);
  attn_kernel<<<1024, 256, 0, stream>>>(Cqkv, Vt, Aout);
  gemm_bt<true><<<dim3(8, 64), 256, 0, stream>>>(Aout, Wot, d_out, 8192, 1024, 1024);
}